// Round 9
// baseline (638.580 us; speedup 1.0000x reference)
//
#include <hip/hip_runtime.h>
#include <hip/hip_bf16.h>
#include <math.h>

#define NODES 50000
#define EDGES 800000
#define EP    850000      // EDGES + NODES self loops
#define INCH  64
#define HIDD  96
#define NHEAD 4
#define CHD   24
#define NLAY  4
#define NGRF  1024
#define BNEPS 1e-5f
#define NB    49          // ceil(NODES/1024)

__device__ __forceinline__ float elu1(float v) { return v > 0.f ? v : __expf(v) - 1.f; }

__device__ __forceinline__ unsigned short f2bf(float f) {   // RNE, matches HW
    unsigned u = __float_as_uint(f);
    return (unsigned short)((u + 0x7fffu + ((u >> 16) & 1u)) >> 16);
}

__device__ __forceinline__ float rl_f(float v, int l) {     // readlane broadcast (uniform l)
    return __int_as_float(__builtin_amdgcn_readlane(__float_as_int(v), l));
}

__device__ __forceinline__ float bnorm(float a, const float* __restrict__ bg,
                                       const float* __restrict__ rm, const float* __restrict__ rv,
                                       const float* __restrict__ gamma, const float* __restrict__ beta,
                                       int ch) {
    float hn = a + bg[ch];
    return (hn - rm[ch]) / sqrtf(rv[ch] + BNEPS) * gamma[ch] + beta[ch];
}

__device__ __forceinline__ void edge_sd(int e, const int* __restrict__ S,
                                        const int* __restrict__ D, int& s, int& d) {
    if (e < EDGES) { s = S[e]; d = D[e]; } else { s = e - EDGES; d = s; }
}

// ---------------- CSR build (once per call; graph is layer-invariant) ----------------

__global__ __launch_bounds__(256) void k_count(const int* __restrict__ S, const int* __restrict__ D,
                                               int* __restrict__ cnt) {
    int e = blockIdx.x * blockDim.x + threadIdx.x;
    if (e >= EP) return;
    int s, d; edge_sd(e, S, D, s, d);
    atomicAdd(&cnt[d], 1);
}

__global__ __launch_bounds__(1024) void k_scan1(const int* __restrict__ cnt,
                                                int* __restrict__ off, int* __restrict__ bsum) {
    __shared__ int sd[1024];
    int t = threadIdx.x;
    int i = blockIdx.x * 1024 + t;
    int v = (i < NODES) ? cnt[i] : 0;
    sd[t] = v; __syncthreads();
    for (int o = 1; o < 1024; o <<= 1) {
        int tv = (t >= o) ? sd[t - o] : 0;
        __syncthreads();
        sd[t] += tv; __syncthreads();
    }
    if (i < NODES) off[i] = sd[t] - v;           // exclusive within block
    if (t == 1023) bsum[blockIdx.x] = sd[1023];
}

__global__ void k_scan2(int* __restrict__ bsum, int* __restrict__ off) {
    if (threadIdx.x == 0 && blockIdx.x == 0) {
        int run = 0;
        for (int b = 0; b < NB; ++b) { int tv = bsum[b]; bsum[b] = run; run += tv; }
        off[NODES] = run;                        // == EP
    }
}

__global__ __launch_bounds__(1024) void k_scan3(int* __restrict__ off, const int* __restrict__ bsum,
                                                int* __restrict__ cursor) {
    int i = blockIdx.x * 1024 + threadIdx.x;
    if (i >= NODES) return;
    int o = off[i] + bsum[blockIdx.x];
    off[i] = o;
    cursor[i] = o;
}

__global__ __launch_bounds__(256) void k_scatter(const int* __restrict__ S, const int* __restrict__ D,
                                                 int* __restrict__ cursor, int* __restrict__ csr_src) {
    int e = blockIdx.x * blockDim.x + threadIdx.x;
    if (e >= EP) return;
    int s, d; edge_sd(e, S, D, s, d);
    int pos = atomicAdd(&cursor[d], 1);
    csr_src[pos] = s;
}

// ---------------- dense node kernels ----------------

// h0 = elu(x @ W_in + b_in). W staged in LDS; lane=node, wave-uniform channel group.
__global__ __launch_bounds__(256) void k_in_proj(const float* __restrict__ x,
                                                 const float* __restrict__ W,
                                                 const float* __restrict__ b,
                                                 float* __restrict__ h) {
    __shared__ float Wl[INCH * HIDD];   // 24 KB
    int tid = threadIdx.x;
    for (int i = tid; i < INCH * HIDD / 4; i += 256)
        ((float4*)Wl)[i] = ((const float4*)W)[i];
    __syncthreads();

    int node = blockIdx.x * 64 + (tid & 63);
    if (node >= NODES) return;
    int cbase = (tid >> 6) * CHD;       // 0,24,48,72 (wave-uniform)
    const float* __restrict__ xr = x + (size_t)node * INCH;

    float acc[CHD];
#pragma unroll
    for (int j = 0; j < CHD; ++j) acc[j] = b[cbase + j];

    for (int k0 = 0; k0 < INCH; k0 += 4) {
        float4 xv = *(const float4*)(xr + k0);
        const float xvv[4] = {xv.x, xv.y, xv.z, xv.w};
#pragma unroll
        for (int kk = 0; kk < 4; ++kk) {
#pragma unroll
            for (int j4 = 0; j4 < CHD; j4 += 4) {
                float4 wv = *(const float4*)(&Wl[(k0 + kk) * HIDD + cbase + j4]);
                acc[j4 + 0] = fmaf(xvv[kk], wv.x, acc[j4 + 0]);
                acc[j4 + 1] = fmaf(xvv[kk], wv.y, acc[j4 + 1]);
                acc[j4 + 2] = fmaf(xvv[kk], wv.z, acc[j4 + 2]);
                acc[j4 + 3] = fmaf(xvv[kk], wv.w, acc[j4 + 3]);
            }
        }
    }
    float* hrow = h + (size_t)node * HIDD + cbase;
#pragma unroll
    for (int j = 0; j < CHD; ++j) hrow[j] = elu1(acc[j]);
}

// hp(bf16-packed) = h @ Wg[i]; fused per-head attention dots (cgroup == head).
// Wg staged in LDS (36 KB) -> uniform-address broadcast ds_read_b128.
__global__ __launch_bounds__(256) void k_proj(const float* __restrict__ h,
                                              const float* __restrict__ W,
                                              const float* __restrict__ asrc,
                                              const float* __restrict__ adst,
                                              unsigned* __restrict__ hpb,   // [N][48] packed bf16x2
                                              float* __restrict__ as_,
                                              float* __restrict__ ad_) {
    __shared__ float Wl[HIDD * HIDD];   // 36 KB
    int tid = threadIdx.x;
    for (int i = tid; i < HIDD * HIDD / 4; i += 256)
        ((float4*)Wl)[i] = ((const float4*)W)[i];
    __syncthreads();

    int node = blockIdx.x * 64 + (tid & 63);
    if (node >= NODES) return;
    int head = tid >> 6;                 // 0..3 (wave-uniform)
    int cbase = head * CHD;
    const float* __restrict__ hr = h + (size_t)node * HIDD;

    float acc[CHD] = {};
    for (int k0 = 0; k0 < HIDD; k0 += 4) {
        float4 hv = *(const float4*)(hr + k0);
        const float hvv[4] = {hv.x, hv.y, hv.z, hv.w};
#pragma unroll
        for (int kk = 0; kk < 4; ++kk) {
#pragma unroll
            for (int j4 = 0; j4 < CHD; j4 += 4) {
                float4 wv = *(const float4*)(&Wl[(k0 + kk) * HIDD + cbase + j4]);
                acc[j4 + 0] = fmaf(hvv[kk], wv.x, acc[j4 + 0]);
                acc[j4 + 1] = fmaf(hvv[kk], wv.y, acc[j4 + 1]);
                acc[j4 + 2] = fmaf(hvv[kk], wv.z, acc[j4 + 2]);
                acc[j4 + 3] = fmaf(hvv[kk], wv.w, acc[j4 + 3]);
            }
        }
    }
    unsigned* orow = hpb + (size_t)node * (HIDD / 2) + cbase / 2;
#pragma unroll
    for (int j = 0; j < CHD; j += 2)
        orow[j / 2] = (unsigned)f2bf(acc[j]) | ((unsigned)f2bf(acc[j + 1]) << 16);

    const float* __restrict__ s = asrc + head * CHD;
    const float* __restrict__ d = adst + head * CHD;
    float sa = 0.f, da = 0.f;
#pragma unroll
    for (int j = 0; j < CHD; ++j) { sa = fmaf(acc[j], s[j], sa); da = fmaf(acc[j], d[j], da); }
    as_[node * NHEAD + head] = sa;
    ad_[node * NHEAD + head] = da;
}

// ---------------- fused edge phase, single pass, readlane broadcast ----------------
// alpha = exp(leaky(as+ad)) / z (max-sub cancels exactly in p/z; |ev| << 88, no overflow).
// Broadcast of (src, p) to gather lanes uses v_readlane with COMPILE-TIME lane index
// (unrolled j*4) -> zero ds_bpermute traffic on the CU-shared LDS pipe.

__global__ __launch_bounds__(256) void k_edge(const int* __restrict__ off,
                                              const int* __restrict__ csr,
                                              const float* __restrict__ as_,
                                              const float* __restrict__ ad_,
                                              const unsigned* __restrict__ hpb,
                                              const float* __restrict__ bg,
                                              const float* __restrict__ gamma,
                                              const float* __restrict__ beta,
                                              const float* __restrict__ rm,
                                              const float* __restrict__ rv,
                                              float* __restrict__ h,
                                              const int* __restrict__ batch,
                                              float* __restrict__ pooled) {
    int node = blockIdx.x * 4 + (threadIdx.x >> 6);
    if (node >= NODES) return;
    int lane = threadIdx.x & 63;
    int beg = off[node], end = off[node + 1];

    int hd = lane & 3, slot = lane >> 2;            // alpha role: edge slot x head
    float adv = ad_[node * NHEAD + hd];
    const int hh = (lane < 48) ? (lane / 12) : 0;   // gather role: head of channel pair
    const bool gl = (lane < 48);

    float acc0 = 0.f, acc1 = 0.f, z = 0.f;
    for (int c0 = beg; c0 < end; c0 += 16) {
        int i = c0 + slot;
        int sreg = 0; float p = 0.f;
        if (i < end) {
            sreg = csr[i];
            float ev = as_[sreg * NHEAD + hd] + adv;
            ev = ev > 0.f ? ev : 0.2f * ev;
            p = __expf(ev);                          // unnormalized
        }
        z += p;
#pragma unroll
        for (int j = 0; j < 16; ++j) {
            int   sv = __builtin_amdgcn_readlane(sreg, j * 4);   // SGPR broadcast
            float p0 = rl_f(p, j * 4 + 0);
            float p1 = rl_f(p, j * 4 + 1);
            float p2 = rl_f(p, j * 4 + 2);
            float p3 = rl_f(p, j * 4 + 3);
            float plo = (hh & 1) ? p1 : p0;
            float phi = (hh & 1) ? p3 : p2;
            float al  = (hh & 2) ? phi : plo;        // alpha for this lane's head (0 if masked)
            if (gl) {
                unsigned u = hpb[(size_t)sv * (HIDD / 2) + lane];  // saddr + const voffset
                acc0 = fmaf(__uint_as_float(u << 16),         al, acc0);
                acc1 = fmaf(__uint_as_float(u & 0xffff0000u), al, acc1);
            }
        }
    }
    // z totals per head (4-step xor reduce over the 16 slots)
#pragma unroll
    for (int o = 4; o < 64; o <<= 1) z += __shfl_xor(z, o);
    float z0 = rl_f(z, 0), z1 = rl_f(z, 1), z2 = rl_f(z, 2), z3 = rl_f(z, 3);
    float zlo = (hh & 1) ? z1 : z0;
    float zhi = (hh & 1) ? z3 : z2;
    float zh  = (hh & 2) ? zhi : zlo;

    if (gl) {
        float izh = 1.f / zh;              // z > 0 guaranteed (self-loop)
        acc0 *= izh; acc1 *= izh;
        int ch0 = 2 * lane, ch1 = ch0 + 1;
        float hn0 = bnorm(acc0, bg, rm, rv, gamma, beta, ch0);
        float hn1 = bnorm(acc1, bg, rm, rv, gamma, beta, ch1);
        float2 hv = *(float2*)(h + (size_t)node * HIDD + ch0);
        hv.x += elu1(hn0);
        hv.y += elu1(hn1);
        *(float2*)(h + (size_t)node * HIDD + ch0) = hv;
        int gi = batch[node] * HIDD;
        atomicAdd(&pooled[gi + ch0], hv.x);
        atomicAdd(&pooled[gi + ch1], hv.y);
    }
}

// ---------------- per-graph MLP head ----------------

__global__ __launch_bounds__(128) void k_head(const float* __restrict__ pooled,
                                              const float* __restrict__ Wjk, const float* __restrict__ bjk,
                                              const float* __restrict__ Wh1, const float* __restrict__ bh1,
                                              const float* __restrict__ Wh2, const float* __restrict__ bh2,
                                              float* __restrict__ out) {
    __shared__ float pin[NLAY * HIDD];
    __shared__ float z1[HIDD];
    __shared__ float z2[HIDD];
    int g = blockIdx.x, tid = threadIdx.x;
    for (int idx = tid; idx < NLAY * HIDD; idx += blockDim.x) {
        int l = idx / HIDD, c = idx % HIDD;
        pin[idx] = pooled[(size_t)l * NGRF * HIDD + (size_t)g * HIDD + c];
    }
    __syncthreads();
    for (int c = tid; c < HIDD; c += blockDim.x) {
        float a = bjk[c];
        for (int k = 0; k < NLAY * HIDD; ++k) a = fmaf(pin[k], Wjk[k * HIDD + c], a);
        z1[c] = elu1(a);
    }
    __syncthreads();
    for (int c = tid; c < HIDD; c += blockDim.x) {
        float a = bh1[c];
#pragma unroll
        for (int k = 0; k < HIDD; ++k) a = fmaf(z1[k], Wh1[k * HIDD + c], a);
        z2[c] = fmaxf(a, 0.f);
    }
    __syncthreads();
    if (tid < 64) {
        float a = 0.f;
        for (int k = tid; k < HIDD; k += 64) a = fmaf(z2[k], Wh2[k], a);
#pragma unroll
        for (int o = 32; o > 0; o >>= 1) a += __shfl_down(a, o);
        if (tid == 0) out[g] = a + bh2[0];
    }
}

extern "C" void kernel_launch(void* const* d_in, const int* in_sizes, int n_in,
                              void* d_out, int out_size, void* d_ws, size_t ws_size,
                              hipStream_t stream) {
    const float* x     = (const float*)d_in[0];
    const int*   ei    = (const int*)d_in[1];
    const int*   batch = (const int*)d_in[2];
    const float* W_in  = (const float*)d_in[3];
    const float* b_in  = (const float*)d_in[4];
    const float* Wg    = (const float*)d_in[5];
    const float* att_s = (const float*)d_in[6];
    const float* att_d = (const float*)d_in[7];
    const float* bg    = (const float*)d_in[8];
    const float* gamma = (const float*)d_in[9];
    const float* beta  = (const float*)d_in[10];
    const float* rm    = (const float*)d_in[11];
    const float* rv    = (const float*)d_in[12];
    const float* Wjk   = (const float*)d_in[13];
    const float* bjk   = (const float*)d_in[14];
    const float* Wh1   = (const float*)d_in[15];
    const float* bh1   = (const float*)d_in[16];
    const float* Wh2   = (const float*)d_in[17];
    const float* bh2   = (const float*)d_in[18];
    float* out = (float*)d_out;

    const int* S = ei;
    const int* Dd = ei + EDGES;

    // workspace layout
    float* ws = (float*)d_ws;
    float*    h      = ws;                               // N*96 f32
    float*    as_    = h    + (size_t)NODES * HIDD;      // N*4
    float*    ad_    = as_  + (size_t)NODES * NHEAD;     // N*4
    float*    pooled = ad_  + (size_t)NODES * NHEAD;     // L*G*96
    unsigned* hpb    = (unsigned*)(pooled + (size_t)NLAY * NGRF * HIDD); // N*48 (bf16x2)
    int*      off    = (int*)(hpb + (size_t)NODES * (HIDD / 2));  // N+1
    int*      cursor = off    + NODES + 1;               // N
    int*      csr    = cursor + NODES;                   // EP
    int*      cnt    = csr    + EP;                      // N
    int*      bsum   = cnt    + NODES;                   // NB

    hipMemsetAsync(pooled, 0, sizeof(float) * NLAY * NGRF * HIDD, stream);
    hipMemsetAsync(cnt, 0, sizeof(int) * NODES, stream);

    const int TB = 256;
    int gE    = (EP + TB - 1) / TB;
    int gTile = (NODES + 63) / 64;   // 782 blocks, 64 nodes each
    int gWave = NODES / 4;           // 12500

    // CSR build (graph is identical across layers)
    k_count<<<gE, TB, 0, stream>>>(S, Dd, cnt);
    k_scan1<<<NB, 1024, 0, stream>>>(cnt, off, bsum);
    k_scan2<<<1, 64, 0, stream>>>(bsum, off);
    k_scan3<<<NB, 1024, 0, stream>>>(off, bsum, cursor);
    k_scatter<<<gE, TB, 0, stream>>>(S, Dd, cursor, csr);

    k_in_proj<<<gTile, TB, 0, stream>>>(x, W_in, b_in, h);

    for (int i = 0; i < NLAY; ++i) {
        k_proj<<<gTile, TB, 0, stream>>>(h, Wg + (size_t)i * HIDD * HIDD,
                                         att_s + i * NHEAD * CHD, att_d + i * NHEAD * CHD,
                                         hpb, as_, ad_);
        k_edge<<<gWave, TB, 0, stream>>>(off, csr, as_, ad_, hpb,
                                         bg + i * HIDD, gamma + i * HIDD, beta + i * HIDD,
                                         rm + i * HIDD, rv + i * HIDD, h, batch,
                                         pooled + (size_t)i * NGRF * HIDD);
    }

    k_head<<<NGRF, 128, 0, stream>>>(pooled, Wjk, bjk, Wh1, bh1, Wh2, bh2, out);
}

// Round 10
// 625.354 us; speedup vs baseline: 1.0211x; 1.0211x over previous
//
#include <hip/hip_runtime.h>
#include <hip/hip_bf16.h>
#include <math.h>

#define NODES 50000
#define EDGES 800000
#define EP    850000      // EDGES + NODES self loops
#define INCH  64
#define HIDD  96
#define NHEAD 4
#define CHD   24
#define NLAY  4
#define NGRF  1024
#define BNEPS 1e-5f
#define NB    49          // ceil(NODES/1024)

__device__ __forceinline__ float elu1(float v) { return v > 0.f ? v : __expf(v) - 1.f; }

__device__ __forceinline__ unsigned short f2bf(float f) {   // RNE, matches HW
    unsigned u = __float_as_uint(f);
    return (unsigned short)((u + 0x7fffu + ((u >> 16) & 1u)) >> 16);
}

__device__ __forceinline__ float rl_f(float v, int l) {     // readlane broadcast (uniform l)
    return __int_as_float(__builtin_amdgcn_readlane(__float_as_int(v), l));
}

__device__ __forceinline__ float bnorm(float a, const float* __restrict__ bg,
                                       const float* __restrict__ rm, const float* __restrict__ rv,
                                       const float* __restrict__ gamma, const float* __restrict__ beta,
                                       int ch) {
    float hn = a + bg[ch];
    return (hn - rm[ch]) / sqrtf(rv[ch] + BNEPS) * gamma[ch] + beta[ch];
}

__device__ __forceinline__ void edge_sd(int e, const int* __restrict__ S,
                                        const int* __restrict__ D, int& s, int& d) {
    if (e < EDGES) { s = S[e]; d = D[e]; } else { s = e - EDGES; d = s; }
}

// ---------------- CSR build (once per call; graph is layer-invariant) ----------------

__global__ __launch_bounds__(256) void k_count(const int* __restrict__ S, const int* __restrict__ D,
                                               int* __restrict__ cnt) {
    int e = blockIdx.x * blockDim.x + threadIdx.x;
    if (e >= EP) return;
    int s, d; edge_sd(e, S, D, s, d);
    atomicAdd(&cnt[d], 1);
}

__global__ __launch_bounds__(1024) void k_scan1(const int* __restrict__ cnt,
                                                int* __restrict__ off, int* __restrict__ bsum) {
    __shared__ int sd[1024];
    int t = threadIdx.x;
    int i = blockIdx.x * 1024 + t;
    int v = (i < NODES) ? cnt[i] : 0;
    sd[t] = v; __syncthreads();
    for (int o = 1; o < 1024; o <<= 1) {
        int tv = (t >= o) ? sd[t - o] : 0;
        __syncthreads();
        sd[t] += tv; __syncthreads();
    }
    if (i < NODES) off[i] = sd[t] - v;           // exclusive within block
    if (t == 1023) bsum[blockIdx.x] = sd[1023];
}

__global__ void k_scan2(int* __restrict__ bsum, int* __restrict__ off) {
    if (threadIdx.x == 0 && blockIdx.x == 0) {
        int run = 0;
        for (int b = 0; b < NB; ++b) { int tv = bsum[b]; bsum[b] = run; run += tv; }
        off[NODES] = run;                        // == EP
    }
}

__global__ __launch_bounds__(1024) void k_scan3(int* __restrict__ off, const int* __restrict__ bsum,
                                                int* __restrict__ cursor) {
    int i = blockIdx.x * 1024 + threadIdx.x;
    if (i >= NODES) return;
    int o = off[i] + bsum[blockIdx.x];
    off[i] = o;
    cursor[i] = o;
}

__global__ __launch_bounds__(256) void k_scatter(const int* __restrict__ S, const int* __restrict__ D,
                                                 int* __restrict__ cursor, int* __restrict__ csr_src) {
    int e = blockIdx.x * blockDim.x + threadIdx.x;
    if (e >= EP) return;
    int s, d; edge_sd(e, S, D, s, d);
    int pos = atomicAdd(&cursor[d], 1);
    csr_src[pos] = s;
}

// ---------------- dense node kernels ----------------

// h0 = elu(x @ W_in + b_in). W staged in LDS; lane=node, wave-uniform channel group.
__global__ __launch_bounds__(256) void k_in_proj(const float* __restrict__ x,
                                                 const float* __restrict__ W,
                                                 const float* __restrict__ b,
                                                 float* __restrict__ h) {
    __shared__ float Wl[INCH * HIDD];   // 24 KB
    int tid = threadIdx.x;
    for (int i = tid; i < INCH * HIDD / 4; i += 256)
        ((float4*)Wl)[i] = ((const float4*)W)[i];
    __syncthreads();

    int node = blockIdx.x * 64 + (tid & 63);
    if (node >= NODES) return;
    int cbase = (tid >> 6) * CHD;       // 0,24,48,72 (wave-uniform)
    const float* __restrict__ xr = x + (size_t)node * INCH;

    float acc[CHD];
#pragma unroll
    for (int j = 0; j < CHD; ++j) acc[j] = b[cbase + j];

    for (int k0 = 0; k0 < INCH; k0 += 4) {
        float4 xv = *(const float4*)(xr + k0);
        const float xvv[4] = {xv.x, xv.y, xv.z, xv.w};
#pragma unroll
        for (int kk = 0; kk < 4; ++kk) {
#pragma unroll
            for (int j4 = 0; j4 < CHD; j4 += 4) {
                float4 wv = *(const float4*)(&Wl[(k0 + kk) * HIDD + cbase + j4]);
                acc[j4 + 0] = fmaf(xvv[kk], wv.x, acc[j4 + 0]);
                acc[j4 + 1] = fmaf(xvv[kk], wv.y, acc[j4 + 1]);
                acc[j4 + 2] = fmaf(xvv[kk], wv.z, acc[j4 + 2]);
                acc[j4 + 3] = fmaf(xvv[kk], wv.w, acc[j4 + 3]);
            }
        }
    }
    float* hrow = h + (size_t)node * HIDD + cbase;
#pragma unroll
    for (int j = 0; j < CHD; ++j) hrow[j] = elu1(acc[j]);
}

// hp(bf16-packed) = h @ Wg[i]; fused per-head attention dots (cgroup == head).
// Wg staged in LDS (36 KB) -> uniform-address broadcast ds_read_b128.
__global__ __launch_bounds__(256) void k_proj(const float* __restrict__ h,
                                              const float* __restrict__ W,
                                              const float* __restrict__ asrc,
                                              const float* __restrict__ adst,
                                              unsigned* __restrict__ hpb,   // [N][48] packed bf16x2
                                              float* __restrict__ as_,
                                              float* __restrict__ ad_) {
    __shared__ float Wl[HIDD * HIDD];   // 36 KB
    int tid = threadIdx.x;
    for (int i = tid; i < HIDD * HIDD / 4; i += 256)
        ((float4*)Wl)[i] = ((const float4*)W)[i];
    __syncthreads();

    int node = blockIdx.x * 64 + (tid & 63);
    if (node >= NODES) return;
    int head = tid >> 6;                 // 0..3 (wave-uniform)
    int cbase = head * CHD;
    const float* __restrict__ hr = h + (size_t)node * HIDD;

    float acc[CHD] = {};
    for (int k0 = 0; k0 < HIDD; k0 += 4) {
        float4 hv = *(const float4*)(hr + k0);
        const float hvv[4] = {hv.x, hv.y, hv.z, hv.w};
#pragma unroll
        for (int kk = 0; kk < 4; ++kk) {
#pragma unroll
            for (int j4 = 0; j4 < CHD; j4 += 4) {
                float4 wv = *(const float4*)(&Wl[(k0 + kk) * HIDD + cbase + j4]);
                acc[j4 + 0] = fmaf(hvv[kk], wv.x, acc[j4 + 0]);
                acc[j4 + 1] = fmaf(hvv[kk], wv.y, acc[j4 + 1]);
                acc[j4 + 2] = fmaf(hvv[kk], wv.z, acc[j4 + 2]);
                acc[j4 + 3] = fmaf(hvv[kk], wv.w, acc[j4 + 3]);
            }
        }
    }
    unsigned* orow = hpb + (size_t)node * (HIDD / 2) + cbase / 2;
#pragma unroll
    for (int j = 0; j < CHD; j += 2)
        orow[j / 2] = (unsigned)f2bf(acc[j]) | ((unsigned)f2bf(acc[j + 1]) << 16);

    const float* __restrict__ s = asrc + head * CHD;
    const float* __restrict__ d = adst + head * CHD;
    float sa = 0.f, da = 0.f;
#pragma unroll
    for (int j = 0; j < CHD; ++j) { sa = fmaf(acc[j], s[j], sa); da = fmaf(acc[j], d[j], da); }
    as_[node * NHEAD + head] = sa;
    ad_[node * NHEAD + head] = da;
}

// ---------------- fused edge phase, single pass ----------------
// alpha = exp(leaky(as+ad)) / z (max-sub cancels exactly in p/z; |ev| << 88, no overflow).
// Phase A: lane (slot,head) computes unnormalized p, stores to wave-private LDS (plds[tid]).
// Phase B (unrolled 16): src via readlane -> SGPR row base (SALU addressing, saddr load);
// alpha via broadcast ds_read with compile-time offset. Masked slots carry p=0 -> branchless.

__global__ __launch_bounds__(256) void k_edge(const int* __restrict__ off,
                                              const int* __restrict__ csr,
                                              const float* __restrict__ as_,
                                              const float* __restrict__ ad_,
                                              const unsigned* __restrict__ hpb,
                                              const float* __restrict__ bg,
                                              const float* __restrict__ gamma,
                                              const float* __restrict__ beta,
                                              const float* __restrict__ rm,
                                              const float* __restrict__ rv,
                                              float* __restrict__ h,
                                              const int* __restrict__ batch,
                                              float* __restrict__ pooled) {
    __shared__ float plds[256];                     // [wave][slot][head] flat == [tid]
    int tid = threadIdx.x;
    int lane = tid & 63;
    int node = __builtin_amdgcn_readfirstlane(blockIdx.x * 4 + (tid >> 6));  // grid exact: node < NODES
    int beg = off[node], end = off[node + 1];       // uniform -> s_load

    int hd = lane & 3, slot = lane >> 2;            // alpha role: edge slot x head
    float adv = ad_[node * NHEAD + hd];
    const int hh = (lane < 48) ? (lane / 12) : 0;   // gather role: head of channel pair
    const bool gl = (lane < 48);
    const int wbase = tid & 192;                    // wave's plds region (w*64)

    float acc0 = 0.f, acc1 = 0.f, z = 0.f;
    for (int c0 = beg; c0 < end; c0 += 16) {
        int i = c0 + slot;
        int ii = min(i, end - 1);                   // clamp: end>beg (self-loop)
        int sreg = csr[ii];
        float ev = as_[sreg * NHEAD + hd] + adv;
        ev = ev > 0.f ? ev : 0.2f * ev;
        float p = (i < end) ? __expf(ev) : 0.f;     // unnormalized; 0 for masked slots
        z += p;
        plds[tid] = p;                              // 1 ds_write, wave-private
#pragma unroll
        for (int j = 0; j < 16; ++j) {
            int sv = __builtin_amdgcn_readlane(sreg, j * 4);   // SGPR src id
            float al = plds[wbase + j * 4 + hh];    // broadcast ds_read, imm offset
            if (gl) {
                const unsigned* rowp = hpb + (size_t)sv * (HIDD / 2);  // SALU base
                unsigned u = rowp[lane];
                acc0 = fmaf(__uint_as_float(u << 16),         al, acc0);
                acc1 = fmaf(__uint_as_float(u & 0xffff0000u), al, acc1);
            }
        }
    }
    // z totals per head (4-step xor reduce over the 16 slots)
#pragma unroll
    for (int o = 4; o < 64; o <<= 1) z += __shfl_xor(z, o);
    float z0 = rl_f(z, 0), z1 = rl_f(z, 1), z2 = rl_f(z, 2), z3 = rl_f(z, 3);
    float zlo = (hh & 1) ? z1 : z0;
    float zhi = (hh & 1) ? z3 : z2;
    float zh  = (hh & 2) ? zhi : zlo;

    if (gl) {
        float izh = 1.f / zh;              // z > 0 guaranteed (self-loop)
        acc0 *= izh; acc1 *= izh;
        int ch0 = 2 * lane, ch1 = ch0 + 1;
        float hn0 = bnorm(acc0, bg, rm, rv, gamma, beta, ch0);
        float hn1 = bnorm(acc1, bg, rm, rv, gamma, beta, ch1);
        float2 hv = *(float2*)(h + (size_t)node * HIDD + ch0);
        hv.x += elu1(hn0);
        hv.y += elu1(hn1);
        *(float2*)(h + (size_t)node * HIDD + ch0) = hv;
        int gi = batch[node] * HIDD;
        atomicAdd(&pooled[gi + ch0], hv.x);
        atomicAdd(&pooled[gi + ch1], hv.y);
    }
}

// ---------------- per-graph MLP head ----------------

__global__ __launch_bounds__(128) void k_head(const float* __restrict__ pooled,
                                              const float* __restrict__ Wjk, const float* __restrict__ bjk,
                                              const float* __restrict__ Wh1, const float* __restrict__ bh1,
                                              const float* __restrict__ Wh2, const float* __restrict__ bh2,
                                              float* __restrict__ out) {
    __shared__ float pin[NLAY * HIDD];
    __shared__ float z1[HIDD];
    __shared__ float z2[HIDD];
    int g = blockIdx.x, tid = threadIdx.x;
    for (int idx = tid; idx < NLAY * HIDD; idx += blockDim.x) {
        int l = idx / HIDD, c = idx % HIDD;
        pin[idx] = pooled[(size_t)l * NGRF * HIDD + (size_t)g * HIDD + c];
    }
    __syncthreads();
    for (int c = tid; c < HIDD; c += blockDim.x) {
        float a = bjk[c];
        for (int k = 0; k < NLAY * HIDD; ++k) a = fmaf(pin[k], Wjk[k * HIDD + c], a);
        z1[c] = elu1(a);
    }
    __syncthreads();
    for (int c = tid; c < HIDD; c += blockDim.x) {
        float a = bh1[c];
#pragma unroll
        for (int k = 0; k < HIDD; ++k) a = fmaf(z1[k], Wh1[k * HIDD + c], a);
        z2[c] = fmaxf(a, 0.f);
    }
    __syncthreads();
    if (tid < 64) {
        float a = 0.f;
        for (int k = tid; k < HIDD; k += 64) a = fmaf(z2[k], Wh2[k], a);
#pragma unroll
        for (int o = 32; o > 0; o >>= 1) a += __shfl_down(a, o);
        if (tid == 0) out[g] = a + bh2[0];
    }
}

extern "C" void kernel_launch(void* const* d_in, const int* in_sizes, int n_in,
                              void* d_out, int out_size, void* d_ws, size_t ws_size,
                              hipStream_t stream) {
    const float* x     = (const float*)d_in[0];
    const int*   ei    = (const int*)d_in[1];
    const int*   batch = (const int*)d_in[2];
    const float* W_in  = (const float*)d_in[3];
    const float* b_in  = (const float*)d_in[4];
    const float* Wg    = (const float*)d_in[5];
    const float* att_s = (const float*)d_in[6];
    const float* att_d = (const float*)d_in[7];
    const float* bg    = (const float*)d_in[8];
    const float* gamma = (const float*)d_in[9];
    const float* beta  = (const float*)d_in[10];
    const float* rm    = (const float*)d_in[11];
    const float* rv    = (const float*)d_in[12];
    const float* Wjk   = (const float*)d_in[13];
    const float* bjk   = (const float*)d_in[14];
    const float* Wh1   = (const float*)d_in[15];
    const float* bh1   = (const float*)d_in[16];
    const float* Wh2   = (const float*)d_in[17];
    const float* bh2   = (const float*)d_in[18];
    float* out = (float*)d_out;

    const int* S = ei;
    const int* Dd = ei + EDGES;

    // workspace layout
    float* ws = (float*)d_ws;
    float*    h      = ws;                               // N*96 f32
    float*    as_    = h    + (size_t)NODES * HIDD;      // N*4
    float*    ad_    = as_  + (size_t)NODES * NHEAD;     // N*4
    float*    pooled = ad_  + (size_t)NODES * NHEAD;     // L*G*96
    unsigned* hpb    = (unsigned*)(pooled + (size_t)NLAY * NGRF * HIDD); // N*48 (bf16x2)
    int*      off    = (int*)(hpb + (size_t)NODES * (HIDD / 2));  // N+1
    int*      cursor = off    + NODES + 1;               // N
    int*      csr    = cursor + NODES;                   // EP (+16 pad)
    int*      cnt    = csr    + EP + 16;                 // N
    int*      bsum   = cnt    + NODES;                   // NB

    hipMemsetAsync(pooled, 0, sizeof(float) * NLAY * NGRF * HIDD, stream);
    hipMemsetAsync(cnt, 0, sizeof(int) * NODES, stream);

    const int TB = 256;
    int gE    = (EP + TB - 1) / TB;
    int gTile = (NODES + 63) / 64;   // 782 blocks, 64 nodes each
    int gWave = NODES / 4;           // 12500 (exact: 4 nodes/block)

    // CSR build (graph is identical across layers)
    k_count<<<gE, TB, 0, stream>>>(S, Dd, cnt);
    k_scan1<<<NB, 1024, 0, stream>>>(cnt, off, bsum);
    k_scan2<<<1, 64, 0, stream>>>(bsum, off);
    k_scan3<<<NB, 1024, 0, stream>>>(off, bsum, cursor);
    k_scatter<<<gE, TB, 0, stream>>>(S, Dd, cursor, csr);

    k_in_proj<<<gTile, TB, 0, stream>>>(x, W_in, b_in, h);

    for (int i = 0; i < NLAY; ++i) {
        k_proj<<<gTile, TB, 0, stream>>>(h, Wg + (size_t)i * HIDD * HIDD,
                                         att_s + i * NHEAD * CHD, att_d + i * NHEAD * CHD,
                                         hpb, as_, ad_);
        k_edge<<<gWave, TB, 0, stream>>>(off, csr, as_, ad_, hpb,
                                         bg + i * HIDD, gamma + i * HIDD, beta + i * HIDD,
                                         rm + i * HIDD, rv + i * HIDD, h, batch,
                                         pooled + (size_t)i * NGRF * HIDD);
    }

    k_head<<<NGRF, 128, 0, stream>>>(pooled, Wjk, bjk, Wh1, bh1, Wh2, bh2, out);
}

// Round 11
// 599.646 us; speedup vs baseline: 1.0649x; 1.0429x over previous
//
#include <hip/hip_runtime.h>
#include <hip/hip_bf16.h>
#include <math.h>

#define NODES 50000
#define EDGES 800000
#define EP    850000      // EDGES + NODES self loops
#define INCH  64
#define HIDD  96
#define NHEAD 4
#define CHD   24
#define NLAY  4
#define NGRF  1024
#define BNEPS 1e-5f
#define NB    49          // ceil(NODES/1024)

__device__ __forceinline__ float elu1(float v) { return v > 0.f ? v : __expf(v) - 1.f; }

__device__ __forceinline__ unsigned short f2bf(float f) {   // RNE, matches HW
    unsigned u = __float_as_uint(f);
    return (unsigned short)((u + 0x7fffu + ((u >> 16) & 1u)) >> 16);
}

__device__ __forceinline__ float rl_f(float v, int l) {     // readlane broadcast (uniform l)
    return __int_as_float(__builtin_amdgcn_readlane(__float_as_int(v), l));
}

__device__ __forceinline__ float bnorm(float a, const float* __restrict__ bg,
                                       const float* __restrict__ rm, const float* __restrict__ rv,
                                       const float* __restrict__ gamma, const float* __restrict__ beta,
                                       int ch) {
    float hn = a + bg[ch];
    return (hn - rm[ch]) / sqrtf(rv[ch] + BNEPS) * gamma[ch] + beta[ch];
}

__device__ __forceinline__ void edge_sd(int e, const int* __restrict__ S,
                                        const int* __restrict__ D, int& s, int& d) {
    if (e < EDGES) { s = S[e]; d = D[e]; } else { s = e - EDGES; d = s; }
}

// ---------------- CSR build (once per call; graph is layer-invariant) ----------------

__global__ __launch_bounds__(256) void k_count(const int* __restrict__ S, const int* __restrict__ D,
                                               int* __restrict__ cnt) {
    int e = blockIdx.x * blockDim.x + threadIdx.x;
    if (e >= EP) return;
    int s, d; edge_sd(e, S, D, s, d);
    atomicAdd(&cnt[d], 1);
}

__global__ __launch_bounds__(1024) void k_scan1(const int* __restrict__ cnt,
                                                int* __restrict__ off, int* __restrict__ bsum) {
    __shared__ int sd[1024];
    int t = threadIdx.x;
    int i = blockIdx.x * 1024 + t;
    int v = (i < NODES) ? cnt[i] : 0;
    sd[t] = v; __syncthreads();
    for (int o = 1; o < 1024; o <<= 1) {
        int tv = (t >= o) ? sd[t - o] : 0;
        __syncthreads();
        sd[t] += tv; __syncthreads();
    }
    if (i < NODES) off[i] = sd[t] - v;           // exclusive within block
    if (t == 1023) bsum[blockIdx.x] = sd[1023];
}

__global__ void k_scan2(int* __restrict__ bsum, int* __restrict__ off) {
    if (threadIdx.x == 0 && blockIdx.x == 0) {
        int run = 0;
        for (int b = 0; b < NB; ++b) { int tv = bsum[b]; bsum[b] = run; run += tv; }
        off[NODES] = run;                        // == EP
    }
}

__global__ __launch_bounds__(1024) void k_scan3(int* __restrict__ off, const int* __restrict__ bsum,
                                                int* __restrict__ cursor) {
    int i = blockIdx.x * 1024 + threadIdx.x;
    if (i >= NODES) return;
    int o = off[i] + bsum[blockIdx.x];
    off[i] = o;
    cursor[i] = o;
}

__global__ __launch_bounds__(256) void k_scatter(const int* __restrict__ S, const int* __restrict__ D,
                                                 int* __restrict__ cursor, int* __restrict__ csr_src) {
    int e = blockIdx.x * blockDim.x + threadIdx.x;
    if (e >= EP) return;
    int s, d; edge_sd(e, S, D, s, d);
    int pos = atomicAdd(&cursor[d], 1);
    csr_src[pos] = s;
}

// ---------------- dense node kernels ----------------

// h0 = elu(x @ W_in + b_in). W staged in LDS; lane=node, wave-uniform channel group.
__global__ __launch_bounds__(256) void k_in_proj(const float* __restrict__ x,
                                                 const float* __restrict__ W,
                                                 const float* __restrict__ b,
                                                 float* __restrict__ h) {
    __shared__ float Wl[INCH * HIDD];   // 24 KB
    int tid = threadIdx.x;
    for (int i = tid; i < INCH * HIDD / 4; i += 256)
        ((float4*)Wl)[i] = ((const float4*)W)[i];
    __syncthreads();

    int node = blockIdx.x * 64 + (tid & 63);
    if (node >= NODES) return;
    int cbase = (tid >> 6) * CHD;       // 0,24,48,72 (wave-uniform)
    const float* __restrict__ xr = x + (size_t)node * INCH;

    float acc[CHD];
#pragma unroll
    for (int j = 0; j < CHD; ++j) acc[j] = b[cbase + j];

    for (int k0 = 0; k0 < INCH; k0 += 4) {
        float4 xv = *(const float4*)(xr + k0);
        const float xvv[4] = {xv.x, xv.y, xv.z, xv.w};
#pragma unroll
        for (int kk = 0; kk < 4; ++kk) {
#pragma unroll
            for (int j4 = 0; j4 < CHD; j4 += 4) {
                float4 wv = *(const float4*)(&Wl[(k0 + kk) * HIDD + cbase + j4]);
                acc[j4 + 0] = fmaf(xvv[kk], wv.x, acc[j4 + 0]);
                acc[j4 + 1] = fmaf(xvv[kk], wv.y, acc[j4 + 1]);
                acc[j4 + 2] = fmaf(xvv[kk], wv.z, acc[j4 + 2]);
                acc[j4 + 3] = fmaf(xvv[kk], wv.w, acc[j4 + 3]);
            }
        }
    }
    float* hrow = h + (size_t)node * HIDD + cbase;
#pragma unroll
    for (int j = 0; j < CHD; ++j) hrow[j] = elu1(acc[j]);
}

// hp(bf16-packed) = h @ Wg[i]; fused per-head attention dots (cgroup == head).
// Wg staged in LDS (36 KB) -> uniform-address broadcast ds_read_b128.
__global__ __launch_bounds__(256) void k_proj(const float* __restrict__ h,
                                              const float* __restrict__ W,
                                              const float* __restrict__ asrc,
                                              const float* __restrict__ adst,
                                              unsigned* __restrict__ hpb,   // [N][48] packed bf16x2
                                              float* __restrict__ as_,
                                              float* __restrict__ ad_) {
    __shared__ float Wl[HIDD * HIDD];   // 36 KB
    int tid = threadIdx.x;
    for (int i = tid; i < HIDD * HIDD / 4; i += 256)
        ((float4*)Wl)[i] = ((const float4*)W)[i];
    __syncthreads();

    int node = blockIdx.x * 64 + (tid & 63);
    if (node >= NODES) return;
    int head = tid >> 6;                 // 0..3 (wave-uniform)
    int cbase = head * CHD;
    const float* __restrict__ hr = h + (size_t)node * HIDD;

    float acc[CHD] = {};
    for (int k0 = 0; k0 < HIDD; k0 += 4) {
        float4 hv = *(const float4*)(hr + k0);
        const float hvv[4] = {hv.x, hv.y, hv.z, hv.w};
#pragma unroll
        for (int kk = 0; kk < 4; ++kk) {
#pragma unroll
            for (int j4 = 0; j4 < CHD; j4 += 4) {
                float4 wv = *(const float4*)(&Wl[(k0 + kk) * HIDD + cbase + j4]);
                acc[j4 + 0] = fmaf(hvv[kk], wv.x, acc[j4 + 0]);
                acc[j4 + 1] = fmaf(hvv[kk], wv.y, acc[j4 + 1]);
                acc[j4 + 2] = fmaf(hvv[kk], wv.z, acc[j4 + 2]);
                acc[j4 + 3] = fmaf(hvv[kk], wv.w, acc[j4 + 3]);
            }
        }
    }
    unsigned* orow = hpb + (size_t)node * (HIDD / 2) + cbase / 2;
#pragma unroll
    for (int j = 0; j < CHD; j += 2)
        orow[j / 2] = (unsigned)f2bf(acc[j]) | ((unsigned)f2bf(acc[j + 1]) << 16);

    const float* __restrict__ s = asrc + head * CHD;
    const float* __restrict__ d = adst + head * CHD;
    float sa = 0.f, da = 0.f;
#pragma unroll
    for (int j = 0; j < CHD; ++j) { sa = fmaf(acc[j], s[j], sa); da = fmaf(acc[j], d[j], da); }
    as_[node * NHEAD + head] = sa;
    ad_[node * NHEAD + head] = da;
}

// ---------------- fused edge phase: 2 nodes per wave (2x memory-level parallelism) ----------------
// alpha = exp(leaky(as+ad)) / z (max-sub cancels in p/z; |ev| << 88, no overflow).
// Per iteration BOTH nodes' chunks run: phase A (p -> wave LDS), then 2x16 unrolled gathers
// issue before the FMA waits -> ~32 loads in flight per wait instead of 16.

__global__ __launch_bounds__(256) void k_edge(const int* __restrict__ off,
                                              const int* __restrict__ csr,
                                              const float* __restrict__ as_,
                                              const float* __restrict__ ad_,
                                              const unsigned* __restrict__ hpb,
                                              const float* __restrict__ bg,
                                              const float* __restrict__ gamma,
                                              const float* __restrict__ beta,
                                              const float* __restrict__ rm,
                                              const float* __restrict__ rv,
                                              float* __restrict__ h,
                                              const int* __restrict__ batch,
                                              float* __restrict__ pooled) {
    __shared__ float plds[512];                     // per wave: 128 floats (2 nodes x 64)
    int tid = threadIdx.x;
    int lane = tid & 63;
    int n0 = __builtin_amdgcn_readfirstlane(blockIdx.x * 8 + (tid >> 6) * 2);  // exact grid
    int n1 = n0 + 1;
    int beg0 = off[n0], end0 = off[n0 + 1], end1 = off[n0 + 2];
    int beg1 = end0;                                // consecutive nodes share the boundary

    int hd = lane & 3, slot = lane >> 2;            // alpha role: edge slot x head
    float adv0 = ad_[n0 * NHEAD + hd];
    float adv1 = ad_[n1 * NHEAD + hd];
    const int hh = (lane < 48) ? (lane / 12) : 0;   // gather role: head of channel pair
    const bool gl = (lane < 48);
    const int wb = (tid & 192) * 2;                 // wave's plds region (w*128)

    float a00 = 0.f, a01 = 0.f, a10 = 0.f, a11 = 0.f, zA = 0.f, zB = 0.f;
    int ca = beg0, cb = beg1;
    while (ca < end0 || cb < end1) {
        bool doA = ca < end0, doB = cb < end1;      // wave-uniform
        int sA = 0, sB = 0;
        if (doA) {
            int i = ca + slot, ii = min(i, end0 - 1);
            sA = csr[ii];
            float ev = as_[sA * NHEAD + hd] + adv0;
            ev = ev > 0.f ? ev : 0.2f * ev;
            float p = (i < end0) ? __expf(ev) : 0.f;
            zA += p;
            plds[wb + lane] = p;
        }
        if (doB) {
            int i = cb + slot, ii = min(i, end1 - 1);
            sB = csr[ii];
            float ev = as_[sB * NHEAD + hd] + adv1;
            ev = ev > 0.f ? ev : 0.2f * ev;
            float p = (i < end1) ? __expf(ev) : 0.f;
            zB += p;
            plds[wb + 64 + lane] = p;
        }
        if (doA) {
#pragma unroll
            for (int j = 0; j < 16; ++j) {
                int sv = __builtin_amdgcn_readlane(sA, j * 4);
                float al = plds[wb + j * 4 + hh];
                if (gl) {
                    unsigned u = (hpb + (size_t)sv * (HIDD / 2))[lane];
                    a00 = fmaf(__uint_as_float(u << 16),         al, a00);
                    a01 = fmaf(__uint_as_float(u & 0xffff0000u), al, a01);
                }
            }
            ca += 16;
        }
        if (doB) {
#pragma unroll
            for (int j = 0; j < 16; ++j) {
                int sv = __builtin_amdgcn_readlane(sB, j * 4);
                float al = plds[wb + 64 + j * 4 + hh];
                if (gl) {
                    unsigned u = (hpb + (size_t)sv * (HIDD / 2))[lane];
                    a10 = fmaf(__uint_as_float(u << 16),         al, a10);
                    a11 = fmaf(__uint_as_float(u & 0xffff0000u), al, a11);
                }
            }
            cb += 16;
        }
    }
    // z totals per head for both nodes
#pragma unroll
    for (int o = 4; o < 64; o <<= 1) { zA += __shfl_xor(zA, o); zB += __shfl_xor(zB, o); }
    float za0 = rl_f(zA, 0), za1 = rl_f(zA, 1), za2 = rl_f(zA, 2), za3 = rl_f(zA, 3);
    float zb0 = rl_f(zB, 0), zb1 = rl_f(zB, 1), zb2 = rl_f(zB, 2), zb3 = rl_f(zB, 3);
    float zAl = (hh & 1) ? za1 : za0, zAh = (hh & 1) ? za3 : za2;
    float zBl = (hh & 1) ? zb1 : zb0, zBh = (hh & 1) ? zb3 : zb2;
    float zhA = (hh & 2) ? zAh : zAl;
    float zhB = (hh & 2) ? zBh : zBl;

    int g0 = batch[n0], g1 = batch[n1];             // uniform (s_load)
    if (gl) {
        float izA = 1.f / zhA, izB = 1.f / zhB;     // z > 0 guaranteed (self-loop)
        a00 *= izA; a01 *= izA; a10 *= izB; a11 *= izB;
        int ch0 = 2 * lane, ch1 = ch0 + 1;
        float hn00 = bnorm(a00, bg, rm, rv, gamma, beta, ch0);
        float hn01 = bnorm(a01, bg, rm, rv, gamma, beta, ch1);
        float hn10 = bnorm(a10, bg, rm, rv, gamma, beta, ch0);
        float hn11 = bnorm(a11, bg, rm, rv, gamma, beta, ch1);
        float2 hv0 = *(float2*)(h + (size_t)n0 * HIDD + ch0);
        float2 hv1 = *(float2*)(h + (size_t)n1 * HIDD + ch0);
        hv0.x += elu1(hn00); hv0.y += elu1(hn01);
        hv1.x += elu1(hn10); hv1.y += elu1(hn11);
        *(float2*)(h + (size_t)n0 * HIDD + ch0) = hv0;
        *(float2*)(h + (size_t)n1 * HIDD + ch0) = hv1;
        if (g0 == g1) {                             // merged pooled atomics (common: sorted batch)
            atomicAdd(&pooled[g0 * HIDD + ch0], hv0.x + hv1.x);
            atomicAdd(&pooled[g0 * HIDD + ch1], hv0.y + hv1.y);
        } else {
            atomicAdd(&pooled[g0 * HIDD + ch0], hv0.x);
            atomicAdd(&pooled[g0 * HIDD + ch1], hv0.y);
            atomicAdd(&pooled[g1 * HIDD + ch0], hv1.x);
            atomicAdd(&pooled[g1 * HIDD + ch1], hv1.y);
        }
    }
}

// ---------------- per-graph MLP head ----------------

__global__ __launch_bounds__(128) void k_head(const float* __restrict__ pooled,
                                              const float* __restrict__ Wjk, const float* __restrict__ bjk,
                                              const float* __restrict__ Wh1, const float* __restrict__ bh1,
                                              const float* __restrict__ Wh2, const float* __restrict__ bh2,
                                              float* __restrict__ out) {
    __shared__ float pin[NLAY * HIDD];
    __shared__ float z1[HIDD];
    __shared__ float z2[HIDD];
    int g = blockIdx.x, tid = threadIdx.x;
    for (int idx = tid; idx < NLAY * HIDD; idx += blockDim.x) {
        int l = idx / HIDD, c = idx % HIDD;
        pin[idx] = pooled[(size_t)l * NGRF * HIDD + (size_t)g * HIDD + c];
    }
    __syncthreads();
    for (int c = tid; c < HIDD; c += blockDim.x) {
        float a = bjk[c];
        for (int k = 0; k < NLAY * HIDD; ++k) a = fmaf(pin[k], Wjk[k * HIDD + c], a);
        z1[c] = elu1(a);
    }
    __syncthreads();
    for (int c = tid; c < HIDD; c += blockDim.x) {
        float a = bh1[c];
#pragma unroll
        for (int k = 0; k < HIDD; ++k) a = fmaf(z1[k], Wh1[k * HIDD + c], a);
        z2[c] = fmaxf(a, 0.f);
    }
    __syncthreads();
    if (tid < 64) {
        float a = 0.f;
        for (int k = tid; k < HIDD; k += 64) a = fmaf(z2[k], Wh2[k], a);
#pragma unroll
        for (int o = 32; o > 0; o >>= 1) a += __shfl_down(a, o);
        if (tid == 0) out[g] = a + bh2[0];
    }
}

extern "C" void kernel_launch(void* const* d_in, const int* in_sizes, int n_in,
                              void* d_out, int out_size, void* d_ws, size_t ws_size,
                              hipStream_t stream) {
    const float* x     = (const float*)d_in[0];
    const int*   ei    = (const int*)d_in[1];
    const int*   batch = (const int*)d_in[2];
    const float* W_in  = (const float*)d_in[3];
    const float* b_in  = (const float*)d_in[4];
    const float* Wg    = (const float*)d_in[5];
    const float* att_s = (const float*)d_in[6];
    const float* att_d = (const float*)d_in[7];
    const float* bg    = (const float*)d_in[8];
    const float* gamma = (const float*)d_in[9];
    const float* beta  = (const float*)d_in[10];
    const float* rm    = (const float*)d_in[11];
    const float* rv    = (const float*)d_in[12];
    const float* Wjk   = (const float*)d_in[13];
    const float* bjk   = (const float*)d_in[14];
    const float* Wh1   = (const float*)d_in[15];
    const float* bh1   = (const float*)d_in[16];
    const float* Wh2   = (const float*)d_in[17];
    const float* bh2   = (const float*)d_in[18];
    float* out = (float*)d_out;

    const int* S = ei;
    const int* Dd = ei + EDGES;

    // workspace layout
    float* ws = (float*)d_ws;
    float*    h      = ws;                               // N*96 f32
    float*    as_    = h    + (size_t)NODES * HIDD;      // N*4
    float*    ad_    = as_  + (size_t)NODES * NHEAD;     // N*4
    float*    pooled = ad_  + (size_t)NODES * NHEAD;     // L*G*96
    unsigned* hpb    = (unsigned*)(pooled + (size_t)NLAY * NGRF * HIDD); // N*48 (bf16x2)
    int*      off    = (int*)(hpb + (size_t)NODES * (HIDD / 2));  // N+2 (off[N+1] pad read by last wave)
    int*      cursor = off    + NODES + 2;               // N
    int*      csr    = cursor + NODES;                   // EP (+16 pad)
    int*      cnt    = csr    + EP + 16;                 // N
    int*      bsum   = cnt    + NODES;                   // NB

    hipMemsetAsync(pooled, 0, sizeof(float) * NLAY * NGRF * HIDD, stream);
    hipMemsetAsync(cnt, 0, sizeof(int) * NODES, stream);
    hipMemsetAsync(off + NODES + 1, 0, sizeof(int), stream);   // pad (off[N+1]; value irrelevant)

    const int TB = 256;
    int gE    = (EP + TB - 1) / TB;
    int gTile = (NODES + 63) / 64;   // 782 blocks, 64 nodes each
    int gEdge = NODES / 8;           // 6250 (exact: 8 nodes/block, 2 per wave)

    // CSR build (graph is identical across layers)
    k_count<<<gE, TB, 0, stream>>>(S, Dd, cnt);
    k_scan1<<<NB, 1024, 0, stream>>>(cnt, off, bsum);
    k_scan2<<<1, 64, 0, stream>>>(bsum, off);
    k_scan3<<<NB, 1024, 0, stream>>>(off, bsum, cursor);
    k_scatter<<<gE, TB, 0, stream>>>(S, Dd, cursor, csr);

    k_in_proj<<<gTile, TB, 0, stream>>>(x, W_in, b_in, h);

    for (int i = 0; i < NLAY; ++i) {
        k_proj<<<gTile, TB, 0, stream>>>(h, Wg + (size_t)i * HIDD * HIDD,
                                         att_s + i * NHEAD * CHD, att_d + i * NHEAD * CHD,
                                         hpb, as_, ad_);
        k_edge<<<gEdge, TB, 0, stream>>>(off, csr, as_, ad_, hpb,
                                         bg + i * HIDD, gamma + i * HIDD, beta + i * HIDD,
                                         rm + i * HIDD, rv + i * HIDD, h, batch,
                                         pooled + (size_t)i * NGRF * HIDD);
    }

    k_head<<<NGRF, 128, 0, stream>>>(pooled, Wjk, bjk, Wh1, bh1, Wh2, bh2, out);
}